// Round 8
// baseline (1272.315 us; speedup 1.0000x reference)
//
#include <hip/hip_runtime.h>
#include <hip/hip_cooperative_groups.h>

namespace cg = cooperative_groups;

#define T_LEN 2050
#define B_SZ 128
#define NCHUNK 33               // chunks of steps t=1..2049
#define HL2PI 0.91893853320467274178f

// ---------- wave-wide helpers (wave = 64 lanes) ----------
__device__ __forceinline__ float waveMax(float v) {
#pragma unroll
    for (int off = 32; off >= 1; off >>= 1)
        v = fmaxf(v, __shfl_xor(v, off, 64));
    return v;
}
__device__ __forceinline__ float waveSum(float v) {
#pragma unroll
    for (int off = 32; off >= 1; off >>= 1)
        v += __shfl_xor(v, off, 64);
    return v;
}
__device__ __forceinline__ void waveArgmax(float& v, int& idx) {
#pragma unroll
    for (int off = 32; off >= 1; off >>= 1) {
        float ov = __shfl_xor(v, off, 64);
        int   oi = __shfl_xor(idx, off, 64);
        if (ov > v || (ov == v && oi < idx)) { v = ov; idx = oi; }
    }
}
__device__ __forceinline__ void cfence() { asm volatile("" ::: "memory"); }

// register-only broadcast: lane i's value -> SGPR (uniform), zero memory latency
__device__ __forceinline__ float rl(float v, int lane) {
    return __int_as_float(__builtin_amdgcn_readlane(__float_as_int(v), lane));
}

// DPP full-wave reductions (rounds 5-10 proven)
__device__ __forceinline__ float dppSumAll(float v) {
#define SSTEP(ctrl) { int t_ = __builtin_amdgcn_update_dpp(0, __float_as_int(v), ctrl, 0xf, 0xf, true); \
                      v = v + __int_as_float(t_); }
    SSTEP(0x111) SSTEP(0x112) SSTEP(0x114) SSTEP(0x118) SSTEP(0x142) SSTEP(0x143)
#undef SSTEP
    return __int_as_float(__builtin_amdgcn_readlane(__float_as_int(v), 63));
}
__device__ __forceinline__ float dppMaxAll(float v) {
#define MSTEP(ctrl) { int t_ = __builtin_amdgcn_update_dpp(__float_as_int(v), __float_as_int(v), ctrl, 0xf, 0xf, false); \
                      v = fmaxf(v, __int_as_float(t_)); }
    MSTEP(0x111) MSTEP(0x112) MSTEP(0x114) MSTEP(0x118) MSTEP(0x142) MSTEP(0x143)
#undef MSTEP
    return __int_as_float(__builtin_amdgcn_readlane(__float_as_int(v), 63));
}

// ===== emission precompute (EXACT op order, round-2 proven bit-exact) -> buf[b][t][64], m_pre[b][t]
// + FUSED prep (block 0, wave 0): log_softmax(log_A) -> lAg column-major, log_softmax(log_pi).
// Static 17KB LDS costs no occupancy (emis is wave-limited at 8 blocks/CU; 8*17KB < 160KB). =====
extern "C" __global__ __launch_bounds__(256)
void hmm_emis(const float* __restrict__ x,
              const float* __restrict__ means,
              const float* __restrict__ stds,
              float* __restrict__ buf,
              float* __restrict__ m_pre,
              const float* __restrict__ logA_in,
              const float* __restrict__ logpi_in,
              float* __restrict__ lAg,
              float* __restrict__ lpig)
{
    __shared__ float la[64 * 65];
    __shared__ float rowlse[64];

    const int wid = blockIdx.x * 4 + (threadIdx.x >> 6);
    const int j = threadIdx.x & 63;
    const int t = wid >> 7;          // wid = t*128 + b
    const int b = wid & 127;

    const float* xt = x + ((size_t)b * T_LEN + t) * 6;
    float x0 = xt[0], x1 = xt[1], x2 = xt[2], x3 = xt[3];

    float mu0 = means[j * 6 + 0], mu1 = means[j * 6 + 1];
    float mu2 = means[j * 6 + 2], mu3 = means[j * 6 + 3];
    float sg0 = fmaxf(stds[j * 6 + 0], 0.f) + 0.1f;
    float sg1 = fmaxf(stds[j * 6 + 1], 0.f) + 0.1f;
    float sg2 = fmaxf(stds[j * 6 + 2], 0.f) + 0.1f;
    float sg3 = fmaxf(stds[j * 6 + 3], 0.f) + 0.1f;
    float ls0 = logf(sg0), ls1 = logf(sg1), ls2 = logf(sg2), ls3 = logf(sg3);

    float z0 = (x0 - mu0) / sg0, z1 = (x1 - mu1) / sg1;
    float z2 = (x2 - mu2) / sg2, z3 = (x3 - mu3) / sg3;
    float e0 = ((-0.5f * z0) * z0 - ls0) - HL2PI;
    float e1 = ((-0.5f * z1) * z1 - ls1) - HL2PI;
    float e2 = ((-0.5f * z2) * z2 - ls2) - HL2PI;
    float e3 = ((-0.5f * z3) * z3 - ls3) - HL2PI;
    float lp = ((e0 + e1) + e2) + e3;

    buf[((size_t)b * T_LEN + t) * 64 + j] = lp;
    float mm = waveMax(lp);
    if (j == 0) m_pre[(size_t)b * T_LEN + t] = mm;

    // ---- fused prep: block 0, wave 0 only (exact op order, rounds 1..10 proven) ----
    if (blockIdx.x == 0 && threadIdx.x < 64) {
#pragma unroll
        for (int k = 0; k < 64; ++k)
            la[k * 65 + j] = logA_in[k * 64 + j];
        cfence();
        {
            float m = -1e30f;
#pragma unroll
            for (int k = 0; k < 64; ++k) m = fmaxf(m, la[j * 65 + k]);
            float s = 0.f;
#pragma unroll
            for (int k = 0; k < 64; ++k) s += expf(la[j * 65 + k] - m);
            rowlse[j] = m + logf(s);
        }
        cfence();
        {
            float v = logpi_in[j];
            float m = waveMax(v);
            float s = waveSum(expf(v - m));
            lpig[j] = v - (m + logf(s));
        }
        float4* o = (float4*)lAg;
#pragma unroll
        for (int k = 0; k < 16; ++k) {
            float4 v;
            v.x = la[(4 * k + 0) * 65 + j] - rowlse[4 * k + 0];
            v.y = la[(4 * k + 1) * 65 + j] - rowlse[4 * k + 1];
            v.z = la[(4 * k + 2) * 65 + j] - rowlse[4 * k + 2];
            v.w = la[(4 * k + 3) * 65 + j] - rowlse[4 * k + 3];
            o[j * 16 + k] = v;
        }
    }
}

// viterbi reduce: adds elementwise-exact, fmax exactly assoc/comm (max3-fusable)
#define VIT_REDUCE(SRC)                                                   \
    float m0 = -3.4e38f, m1 = -3.4e38f, m2 = -3.4e38f, m3 = -3.4e38f;     \
    _Pragma("unroll")                                                     \
    for (int gq = 0; gq < 4; ++gq) {                                      \
        float s_[16];                                                     \
        _Pragma("unroll")                                                 \
        for (int m_ = 0; m_ < 16; ++m_) s_[m_] = rl((SRC), 16 * gq + m_); \
        __builtin_amdgcn_sched_barrier(0);                                \
        _Pragma("unroll")                                                 \
        for (int k2 = 0; k2 < 4; k2 += 2) {                               \
            const int ia = 16 * gq + 4 * k2;                              \
            const int ib = ia + 4;                                        \
            float a0_ = s_[4*k2+0] + lA[ia+0], b0_ = s_[4*k2+4] + lA[ib+0]; \
            float a1_ = s_[4*k2+1] + lA[ia+1], b1_ = s_[4*k2+5] + lA[ib+1]; \
            float a2_ = s_[4*k2+2] + lA[ia+2], b2_ = s_[4*k2+6] + lA[ib+2]; \
            float a3_ = s_[4*k2+3] + lA[ia+3], b3_ = s_[4*k2+7] + lA[ib+3]; \
            m0 = fmaxf(fmaxf(m0, a0_), b0_);                              \
            m1 = fmaxf(fmaxf(m1, a1_), b1_);                              \
            m2 = fmaxf(fmaxf(m2, a2_), b2_);                              \
            m3 = fmaxf(fmaxf(m3, a3_), b3_);                              \
        }                                                                 \
    }

// ===== main: single wave per chain (round-5 proven structure, unchanged).
// blocks 0..127: forward -> out[b]; blocks 128..255: viterbi -> d in buf, c_last =====
extern "C" __global__ __launch_bounds__(64, 1)
void hmm_main(const float* __restrict__ x,
              const float* __restrict__ means,
              const float* __restrict__ stds,
              const float* __restrict__ lAg,
              const float* __restrict__ lpig,
              float* __restrict__ out,
              float* __restrict__ buf,
              const float* __restrict__ m_pre,
              int* __restrict__ c_last)
{
    __shared__ __align__(16) float xs[12304];     // x[b] (forward half only)

    const int j   = threadIdx.x;
    const int bid = blockIdx.x;
    const bool is_fwd = (bid < B_SZ);
    const int b = is_fwd ? bid : bid - B_SZ;

    float lpi = lpig[j];

    if (is_fwd) {
        // stage x (inline mul-path emissions — rounds 5-9 proven)
        {
            const float4* xg4 = (const float4*)(x + (size_t)b * T_LEN * 6);
            float4* xs4 = (float4*)xs;
            for (int i = j; i < 3075; i += 64) xs4[i] = xg4[i];
        }
        float mu0 = means[j * 6 + 0], mu1 = means[j * 6 + 1];
        float mu2 = means[j * 6 + 2], mu3 = means[j * 6 + 3];
        float sg0 = fmaxf(stds[j * 6 + 0], 0.f) + 0.1f;
        float sg1 = fmaxf(stds[j * 6 + 1], 0.f) + 0.1f;
        float sg2 = fmaxf(stds[j * 6 + 2], 0.f) + 0.1f;
        float sg3 = fmaxf(stds[j * 6 + 3], 0.f) + 0.1f;
        float ls0 = logf(sg0), ls1 = logf(sg1), ls2 = logf(sg2), ls3 = logf(sg3);
        float i0 = 1.f / sg0, i1 = 1.f / sg1, i2 = 1.f / sg2, i3 = 1.f / sg3;
        float cst = -(ls0 + ls1 + ls2 + ls3) - 4.f * HL2PI;

        float Ac[64];
        {
            const float4* g = (const float4*)lAg;
#pragma unroll
            for (int k = 0; k < 16; ++k) {
                float4 v = g[j * 16 + k];
                Ac[4 * k + 0] = __expf(v.x); Ac[4 * k + 1] = __expf(v.y);
                Ac[4 * k + 2] = __expf(v.z); Ac[4 * k + 3] = __expf(v.w);
            }
        }
        cfence();   // xs staged (same-wave in-order DS)

        // t = 0
        float z0 = (xs[0] - mu0) * i0, z1 = (xs[1] - mu1) * i1;
        float z2 = (xs[2] - mu2) * i2, z3 = (xs[3] - mu3) * i3;
        float a0 = (cst - 0.5f * (z0 * z0 + z1 * z1 + z2 * z2 + z3 * z3)) + lpi;
        float m0a = dppMaxAll(a0);
        float u = __expf(a0 - m0a);
        float s0 = dppSumAll(u);
        double acc = (double)(m0a + __logf(s0));
        u *= (1.0f / s0);

        // m_pre ring (4-deep prefetch), wave-uniform broadcast loads
        const float* mp = m_pre + (size_t)b * T_LEN;
        float g0 = mp[1], g1 = mp[2], g2 = mp[3], g3 = mp[4];

#pragma unroll 1
        for (int t = 1; t < T_LEN; ++t) {
            float mm_c = g0; g0 = g1; g1 = g2; g2 = g3;
            int tp = t + 4; if (tp > T_LEN - 1) tp = T_LEN - 1;
            g3 = mp[tp];

            // emission t (mul path; xs reads issued early; independent of u -> overlaps)
            int o = t * 6;
            float y0 = xs[o], y1 = xs[o + 1], y2 = xs[o + 2], y3 = xs[o + 3];
            float w0 = (y0 - mu0) * i0, w1 = (y1 - mu1) * i1;
            float w2 = (y2 - mu2) * i2, w3 = (y3 - mu3) * i3;
            float lp = cst - 0.5f * (w0 * w0 + w1 * w1 + w2 * w2 + w3 * w3);
            float e_c = __expf(lp - mm_c);

            // q_j = sum_i u[i]*A[i][j] via readlane broadcast (register-only)
            float q0 = 0.f, q1 = 0.f, q2 = 0.f, q3 = 0.f;
#pragma unroll
            for (int gq = 0; gq < 4; ++gq) {
                float s[16];
#pragma unroll
                for (int m = 0; m < 16; ++m) s[m] = rl(u, 16 * gq + m);
#pragma unroll
                for (int k2 = 0; k2 < 4; ++k2) {
                    const int i = 16 * gq + 4 * k2;     // i = 4k+c, k ascending per chain
                    q0 = fmaf(s[4 * k2 + 0], Ac[i + 0], q0);
                    q1 = fmaf(s[4 * k2 + 1], Ac[i + 1], q1);
                    q2 = fmaf(s[4 * k2 + 2], Ac[i + 2], q2);
                    q3 = fmaf(s[4 * k2 + 3], Ac[i + 3], q3);
                }
            }
            u = ((q0 + q1) + (q2 + q3)) * e_c;
            acc += (double)mm_c;
            if ((t & 3) == 0) {          // deferred renorm (rounds 9/10 proven)
                float ss = dppSumAll(u);
                acc += (double)__logf(ss);
                u *= (1.0f / ss);
            }
        }
        float sf = dppSumAll(u);
        acc += (double)__logf(sf);
        if (j == 0) out[b] = (float)acc;
    } else {
        // ---------------- VITERBI: readlane broadcast + ring-8 constant-distance prefetch ----------------
        float lA[64];
        {
            const float4* g = (const float4*)lAg;
#pragma unroll
            for (int k = 0; k < 16; ++k) {
                float4 v = g[j * 16 + k];
                lA[4 * k + 0] = v.x; lA[4 * k + 1] = v.y;
                lA[4 * k + 2] = v.z; lA[4 * k + 3] = v.w;
            }
        }
        float* bb = buf + (size_t)b * T_LEN * 64 + j;

        // t = 0: seed dn, fill ring with lp rows 1..8, then overwrite row 0 with d0
        float dn = bb[0] + lpi;
        float lr[8];
#pragma unroll
        for (int i = 0; i < 8; ++i) lr[i] = bb[(size_t)(1 + i) * 64];
        bb[0] = dn;

        // main: t = 1..2040 in 255 groups of 8; ring slots are compile-time
        // indices (no shifts); load (t+8) vs store (t) distance = 2048 B, alias-free.
#pragma unroll 1
        for (int tb = 1; tb <= 2033; tb += 8) {
#pragma unroll
            for (int q = 0; q < 8; ++q) {
                const int t = tb + q;
                float lp_c = lr[q];
                lr[q] = bb[(size_t)(t + 8) * 64];   // max t+8 = 2048, in-bounds
                VIT_REDUCE(dn);
                dn = fmaxf(fmaxf(m0, m1), fmaxf(m2, m3)) + lp_c;
                bb[(size_t)t * 64] = dn;            // overwrite lp row t with d row t
            }
        }
        // row 2049 (distance >= 9 rows from last store: alias-free)
        float l_last = bb[(size_t)2049 * 64];
        // peel t = 2041..2048 from the ring (no loads)
#pragma unroll
        for (int q = 0; q < 8; ++q) {
            const int t = 2041 + q;
            float lp_c = lr[q];
            VIT_REDUCE(dn);
            dn = fmaxf(fmaxf(m0, m1), fmaxf(m2, m3)) + lp_c;
            bb[(size_t)t * 64] = dn;
        }
        // final t = 2049 (d row 2049 never read downstream: no store)
        {
            float lp_c = l_last;
            VIT_REDUCE(dn);
            dn = fmaxf(fmaxf(m0, m1), fmaxf(m2, m3)) + lp_c;
        }

        float vv = dn; int idx = j;
        waveArgmax(vv, idx);
        if (j == 0) c_last[b] = idx;
    }
}

// ===== back: FUSED psi + compose + bound + fill (cooperative, grid.sync between
// phases — device-scope fences cover the cross-XCD handoffs). Grid 768x256 =
// 3 blocks/CU worst-case -> co-residency guaranteed. All phase internals are the
// round-7 proven bodies, grid-strided over 3072 waves. =====
extern "C" __global__ __launch_bounds__(256)
void hmm_back(const float* __restrict__ buf,
              const float* __restrict__ lAg,
              unsigned char* __restrict__ psi,
              unsigned char* __restrict__ mt,
              const int* __restrict__ c_last,
              int* __restrict__ sbg,
              float* __restrict__ out)
{
    cg::grid_group grid = cg::this_grid();
    __shared__ __align__(16) float sd[4][64];
    const int warp = threadIdx.x >> 6;
    const int j = threadIdx.x & 63;
    const int wid = blockIdx.x * 4 + warp;        // 0..3071
    const int NW = 768 * 4;                       // 3072 waves

    // ---------------- phase 1: psi recompute (round-5-verbatim argmax tracker) ----------------
    {
        float lA[64];
        {
            const float4* g = (const float4*)lAg;
#pragma unroll
            for (int k = 0; k < 16; ++k) {
                float4 v = g[j * 16 + k];
                lA[4 * k + 0] = v.x; lA[4 * k + 1] = v.y;
                lA[4 * k + 2] = v.z; lA[4 * k + 3] = v.w;
            }
        }
        const float4* dv = (const float4*)sd[warp];
        const int NP = 2049 * B_SZ;
        for (int p = wid; p < NP; p += NW) {
            const int t = (p >> 7) + 1;
            const int b = p & 127;
            float dval = buf[((size_t)b * T_LEN + (t - 1)) * 64 + j];
            sd[warp][j] = dval;    // same-wave in-order: reads below see it

            float bv0 = -3.4e38f, bv1 = -3.4e38f, bv2 = -3.4e38f, bv3 = -3.4e38f;
            int bi0 = 0, bi1 = 1, bi2 = 2, bi3 = 3;
#pragma unroll
            for (int k = 0; k < 16; ++k) {
                float4 dd = dv[k];
                float v0 = dd.x + lA[4 * k + 0];
                float v1 = dd.y + lA[4 * k + 1];
                float v2 = dd.z + lA[4 * k + 2];
                float v3 = dd.w + lA[4 * k + 3];
                if (v0 > bv0) { bv0 = v0; bi0 = 4 * k + 0; }
                if (v1 > bv1) { bv1 = v1; bi1 = 4 * k + 1; }
                if (v2 > bv2) { bv2 = v2; bi2 = 4 * k + 2; }
                if (v3 > bv3) { bv3 = v3; bi3 = 4 * k + 3; }
            }
            float best = bv0; int bidx = bi0;
            if (bv1 > best || (bv1 == best && bi1 < bidx)) { best = bv1; bidx = bi1; }
            if (bv2 > best || (bv2 == best && bi2 < bidx)) { best = bv2; bidx = bi2; }
            if (bv3 > best || (bv3 == best && bi3 < bidx)) { best = bv3; bidx = bi3; }

            psi[((size_t)t * B_SZ + b) * 64 + j] = (unsigned char)bidx;
        }
    }
    grid.sync();

    // ---------------- phase 2: per-chunk backpointer composition (ds_bpermute walk) ----------------
    for (int w = wid; w < NCHUNK * B_SZ; w += NW) {
        const int g = w % NCHUNK;
        const int b = w / NCHUNK;
        const int e  = (g < NCHUNK - 1) ? g * 64 + 64 : (T_LEN - 1);
        const int t0 = g * 64 + 1;

        int M = j;
        int r[8];
#pragma unroll
        for (int i = 0; i < 8; ++i) {
            int t = e - i;
            r[i] = (t >= t0) ? (int)psi[((size_t)t * B_SZ + b) * 64 + j] : 0;
        }
#pragma unroll 1
        for (int t = e; t >= t0; --t) {
            const int q = (e - t) & 7;
            int row = r[q];
            int tn = t - 8;
            r[q] = (tn >= t0) ? (int)psi[((size_t)tn * B_SZ + b) * 64 + j] : 0;
            M = __builtin_amdgcn_ds_bpermute(M << 2, row);   // M = row[M], per lane
        }
        mt[((size_t)g * B_SZ + b) * 64 + j] = (unsigned char)M;
    }
    grid.sync();

    // ---------------- phase 3: boundary walk (first 128 waves, readlane walk) ----------------
    if (wid < B_SZ) {
        const int b = wid;
        int rows[NCHUNK];                         // lane j holds mt[(q,b)][j]
#pragma unroll
        for (int q = 0; q < NCHUNK; ++q)
            rows[q] = (int)mt[((size_t)q * B_SZ + b) * 64 + j];
        int cur = c_last[b];
#pragma unroll
        for (int q = NCHUNK - 1; q >= 0; --q) {
            cur = __builtin_amdgcn_readlane(rows[q], cur);   // cur = mt_row_q[cur]
            if (j == 0) sbg[b * NCHUNK + q] = cur;
        }
    }
    grid.sync();

    // ---------------- phase 4: chunk fill (psi rows prefetched, readlane walk) ----------------
    for (int w = wid; w < NCHUNK * B_SZ; w += NW) {
        const int g = w % NCHUNK;
        const int b = w / NCHUNK;
        const int cl = c_last[b];
        float* oc = out + B_SZ + (size_t)b * T_LEN;

        const int e  = (g < NCHUNK - 1) ? g * 64 + 64 : (T_LEN - 1);
        const int t0 = g * 64 + 1;
        int s = (g < NCHUNK - 1) ? sbg[b * NCHUNK + g + 1] : cl;
        if (g == NCHUNK - 1 && j == 0) oc[T_LEN - 1] = (float)cl;

        int r[8];
#pragma unroll
        for (int i = 0; i < 8; ++i) {
            int t = e - i;
            r[i] = (t >= t0) ? (int)psi[((size_t)t * B_SZ + b) * 64 + j] : 0;
        }
#pragma unroll 1
        for (int t = e; t >= t0; --t) {
            const int q = (e - t) & 7;
            int row = r[q];
            int tn = t - 8;
            r[q] = (tn >= t0) ? (int)psi[((size_t)tn * B_SZ + b) * 64 + j] : 0;
            s = __builtin_amdgcn_readlane(row, s);           // s = psi_row_t[s]
            if (j == 0) oc[t - 1] = (float)s;
        }
    }
}

extern "C" void kernel_launch(void* const* d_in, const int* in_sizes, int n_in,
                              void* d_out, int out_size, void* d_ws, size_t ws_size,
                              hipStream_t stream)
{
    const float* x      = (const float*)d_in[0];
    const float* means  = (const float*)d_in[1];
    const float* stds   = (const float*)d_in[2];
    const float* logA   = (const float*)d_in[3];
    const float* logpi  = (const float*)d_in[4];
    float* out = (float*)d_out;

    // workspace: 84,255,488 B (proven to fit). m_pre overlaps the psi region:
    // m_pre (1 MB) is consumed by hmm_main and only then does hmm_back overwrite psi.
    // sbg reuses the buf region (buf fully consumed by hmm_back phase 1 before
    // phase 3 writes sbg — grid.sync separates).
    char* base = (char*)d_ws;
    float*         buf   = (float*)base;                                 // 67,174,400 (lp then d, in place)
    unsigned char* psi   = (unsigned char*)(base + 67174400);            // 16,793,600
    float*         m_pre = (float*)(base + 67174400);                    //  1,049,600 (dead after hmm_main)
    unsigned char* mt    = (unsigned char*)(base + 83968000);            //    270,336
    int*           cl    = (int*)(base + 84238336);                      //        512
    float*         lAg   = (float*)(base + 84238848);                    //     16,384
    float*         lpig  = (float*)(base + 84255232);                    //        256
    int*           sbg   = (int*)base;                                   // 16,896 (in dead buf region)

    hipLaunchKernelGGL(hmm_emis, dim3((T_LEN * B_SZ) / 4), dim3(256), 0, stream,
                       x, means, stds, buf, m_pre, logA, logpi, lAg, lpig);
    hipLaunchKernelGGL(hmm_main, dim3(2 * B_SZ), dim3(64), 0, stream,
                       x, means, stds, lAg, lpig, out, buf, m_pre, cl);
    {
        void* bargs[] = { (void*)&buf, (void*)&lAg, (void*)&psi, (void*)&mt,
                          (void*)&cl, (void*)&sbg, (void*)&out };
        hipLaunchCooperativeKernel((void*)hmm_back, dim3(768), dim3(256),
                                   bargs, 0, stream);
    }
}

// Round 9
// 1265.786 us; speedup vs baseline: 1.0052x; 1.0052x over previous
//
#include <hip/hip_runtime.h>

#define T_LEN 2050
#define B_SZ 128
#define NCHUNK 33               // chunks of steps t=1..2049
#define HL2PI 0.91893853320467274178f

// ---------- wave-wide helpers (wave = 64 lanes) ----------
__device__ __forceinline__ float waveMax(float v) {
#pragma unroll
    for (int off = 32; off >= 1; off >>= 1)
        v = fmaxf(v, __shfl_xor(v, off, 64));
    return v;
}
__device__ __forceinline__ float waveSum(float v) {
#pragma unroll
    for (int off = 32; off >= 1; off >>= 1)
        v += __shfl_xor(v, off, 64);
    return v;
}
__device__ __forceinline__ void waveArgmax(float& v, int& idx) {
#pragma unroll
    for (int off = 32; off >= 1; off >>= 1) {
        float ov = __shfl_xor(v, off, 64);
        int   oi = __shfl_xor(idx, off, 64);
        if (ov > v || (ov == v && oi < idx)) { v = ov; idx = oi; }
    }
}
__device__ __forceinline__ void cfence() { asm volatile("" ::: "memory"); }

// register-only broadcast: lane i's value -> SGPR (uniform), zero memory latency
__device__ __forceinline__ float rl(float v, int lane) {
    return __int_as_float(__builtin_amdgcn_readlane(__float_as_int(v), lane));
}

// DPP full-wave reductions (rounds 5-10 proven)
__device__ __forceinline__ float dppSumAll(float v) {
#define SSTEP(ctrl) { int t_ = __builtin_amdgcn_update_dpp(0, __float_as_int(v), ctrl, 0xf, 0xf, true); \
                      v = v + __int_as_float(t_); }
    SSTEP(0x111) SSTEP(0x112) SSTEP(0x114) SSTEP(0x118) SSTEP(0x142) SSTEP(0x143)
#undef SSTEP
    return __int_as_float(__builtin_amdgcn_readlane(__float_as_int(v), 63));
}
__device__ __forceinline__ float dppMaxAll(float v) {
#define MSTEP(ctrl) { int t_ = __builtin_amdgcn_update_dpp(__float_as_int(v), __float_as_int(v), ctrl, 0xf, 0xf, false); \
                      v = fmaxf(v, __int_as_float(t_)); }
    MSTEP(0x111) MSTEP(0x112) MSTEP(0x114) MSTEP(0x118) MSTEP(0x142) MSTEP(0x143)
#undef MSTEP
    return __int_as_float(__builtin_amdgcn_readlane(__float_as_int(v), 63));
}

// ===== emission precompute (EXACT op order, round-2 proven bit-exact) -> buf[b][t][64], m_pre[b][t]
// + FUSED prep (block 0, wave 0, same-wave in-order DS — identical pattern to the
// proven standalone hmm_prep): log_softmax(log_A) -> lAg column-major, log_softmax(log_pi). =====
extern "C" __global__ __launch_bounds__(256)
void hmm_emis(const float* __restrict__ x,
              const float* __restrict__ means,
              const float* __restrict__ stds,
              float* __restrict__ buf,
              float* __restrict__ m_pre,
              const float* __restrict__ logA_in,
              const float* __restrict__ logpi_in,
              float* __restrict__ lAg,
              float* __restrict__ lpig)
{
    __shared__ float la[64 * 65];
    __shared__ float rowlse[64];

    const int wid = blockIdx.x * 4 + (threadIdx.x >> 6);
    const int j = threadIdx.x & 63;
    const int t = wid >> 7;          // wid = t*128 + b
    const int b = wid & 127;

    const float* xt = x + ((size_t)b * T_LEN + t) * 6;
    float x0 = xt[0], x1 = xt[1], x2 = xt[2], x3 = xt[3];

    float mu0 = means[j * 6 + 0], mu1 = means[j * 6 + 1];
    float mu2 = means[j * 6 + 2], mu3 = means[j * 6 + 3];
    float sg0 = fmaxf(stds[j * 6 + 0], 0.f) + 0.1f;
    float sg1 = fmaxf(stds[j * 6 + 1], 0.f) + 0.1f;
    float sg2 = fmaxf(stds[j * 6 + 2], 0.f) + 0.1f;
    float sg3 = fmaxf(stds[j * 6 + 3], 0.f) + 0.1f;
    float ls0 = logf(sg0), ls1 = logf(sg1), ls2 = logf(sg2), ls3 = logf(sg3);

    float z0 = (x0 - mu0) / sg0, z1 = (x1 - mu1) / sg1;
    float z2 = (x2 - mu2) / sg2, z3 = (x3 - mu3) / sg3;
    float e0 = ((-0.5f * z0) * z0 - ls0) - HL2PI;
    float e1 = ((-0.5f * z1) * z1 - ls1) - HL2PI;
    float e2 = ((-0.5f * z2) * z2 - ls2) - HL2PI;
    float e3 = ((-0.5f * z3) * z3 - ls3) - HL2PI;
    float lp = ((e0 + e1) + e2) + e3;

    buf[((size_t)b * T_LEN + t) * 64 + j] = lp;
    float mm = waveMax(lp);
    if (j == 0) m_pre[(size_t)b * T_LEN + t] = mm;

    // ---- fused prep: block 0, wave 0 only (exact op order, rounds 1..10 proven) ----
    if (blockIdx.x == 0 && threadIdx.x < 64) {
#pragma unroll
        for (int k = 0; k < 64; ++k)
            la[k * 65 + j] = logA_in[k * 64 + j];
        cfence();
        {
            float m = -1e30f;
#pragma unroll
            for (int k = 0; k < 64; ++k) m = fmaxf(m, la[j * 65 + k]);
            float s = 0.f;
#pragma unroll
            for (int k = 0; k < 64; ++k) s += expf(la[j * 65 + k] - m);
            rowlse[j] = m + logf(s);
        }
        cfence();
        {
            float v = logpi_in[j];
            float m = waveMax(v);
            float s = waveSum(expf(v - m));
            lpig[j] = v - (m + logf(s));
        }
        float4* o = (float4*)lAg;
#pragma unroll
        for (int k = 0; k < 16; ++k) {
            float4 v;
            v.x = la[(4 * k + 0) * 65 + j] - rowlse[4 * k + 0];
            v.y = la[(4 * k + 1) * 65 + j] - rowlse[4 * k + 1];
            v.z = la[(4 * k + 2) * 65 + j] - rowlse[4 * k + 2];
            v.w = la[(4 * k + 3) * 65 + j] - rowlse[4 * k + 3];
            o[j * 16 + k] = v;
        }
    }
}

// viterbi reduce: adds elementwise-exact, fmax exactly assoc/comm (max3-fusable)
#define VIT_REDUCE(SRC)                                                   \
    float m0 = -3.4e38f, m1 = -3.4e38f, m2 = -3.4e38f, m3 = -3.4e38f;     \
    _Pragma("unroll")                                                     \
    for (int gq = 0; gq < 4; ++gq) {                                      \
        float s_[16];                                                     \
        _Pragma("unroll")                                                 \
        for (int m_ = 0; m_ < 16; ++m_) s_[m_] = rl((SRC), 16 * gq + m_); \
        __builtin_amdgcn_sched_barrier(0);                                \
        _Pragma("unroll")                                                 \
        for (int k2 = 0; k2 < 4; k2 += 2) {                               \
            const int ia = 16 * gq + 4 * k2;                              \
            const int ib = ia + 4;                                        \
            float a0_ = s_[4*k2+0] + lA[ia+0], b0_ = s_[4*k2+4] + lA[ib+0]; \
            float a1_ = s_[4*k2+1] + lA[ia+1], b1_ = s_[4*k2+5] + lA[ib+1]; \
            float a2_ = s_[4*k2+2] + lA[ia+2], b2_ = s_[4*k2+6] + lA[ib+2]; \
            float a3_ = s_[4*k2+3] + lA[ia+3], b3_ = s_[4*k2+7] + lA[ib+3]; \
            m0 = fmaxf(fmaxf(m0, a0_), b0_);                              \
            m1 = fmaxf(fmaxf(m1, a1_), b1_);                              \
            m2 = fmaxf(fmaxf(m2, a2_), b2_);                              \
            m3 = fmaxf(fmaxf(m3, a3_), b3_);                              \
        }                                                                 \
    }

// ===== main: single wave per chain (round-5 proven structure, unchanged).
// blocks 0..127: forward -> out[b]; blocks 128..255: viterbi -> d in buf, c_last =====
extern "C" __global__ __launch_bounds__(64, 1)
void hmm_main(const float* __restrict__ x,
              const float* __restrict__ means,
              const float* __restrict__ stds,
              const float* __restrict__ lAg,
              const float* __restrict__ lpig,
              float* __restrict__ out,
              float* __restrict__ buf,
              const float* __restrict__ m_pre,
              int* __restrict__ c_last)
{
    __shared__ __align__(16) float xs[12304];     // x[b] (forward half only)

    const int j   = threadIdx.x;
    const int bid = blockIdx.x;
    const bool is_fwd = (bid < B_SZ);
    const int b = is_fwd ? bid : bid - B_SZ;

    float lpi = lpig[j];

    if (is_fwd) {
        // stage x (inline mul-path emissions — rounds 5-9 proven)
        {
            const float4* xg4 = (const float4*)(x + (size_t)b * T_LEN * 6);
            float4* xs4 = (float4*)xs;
            for (int i = j; i < 3075; i += 64) xs4[i] = xg4[i];
        }
        float mu0 = means[j * 6 + 0], mu1 = means[j * 6 + 1];
        float mu2 = means[j * 6 + 2], mu3 = means[j * 6 + 3];
        float sg0 = fmaxf(stds[j * 6 + 0], 0.f) + 0.1f;
        float sg1 = fmaxf(stds[j * 6 + 1], 0.f) + 0.1f;
        float sg2 = fmaxf(stds[j * 6 + 2], 0.f) + 0.1f;
        float sg3 = fmaxf(stds[j * 6 + 3], 0.f) + 0.1f;
        float ls0 = logf(sg0), ls1 = logf(sg1), ls2 = logf(sg2), ls3 = logf(sg3);
        float i0 = 1.f / sg0, i1 = 1.f / sg1, i2 = 1.f / sg2, i3 = 1.f / sg3;
        float cst = -(ls0 + ls1 + ls2 + ls3) - 4.f * HL2PI;

        float Ac[64];
        {
            const float4* g = (const float4*)lAg;
#pragma unroll
            for (int k = 0; k < 16; ++k) {
                float4 v = g[j * 16 + k];
                Ac[4 * k + 0] = __expf(v.x); Ac[4 * k + 1] = __expf(v.y);
                Ac[4 * k + 2] = __expf(v.z); Ac[4 * k + 3] = __expf(v.w);
            }
        }
        cfence();   // xs staged (same-wave in-order DS)

        // t = 0
        float z0 = (xs[0] - mu0) * i0, z1 = (xs[1] - mu1) * i1;
        float z2 = (xs[2] - mu2) * i2, z3 = (xs[3] - mu3) * i3;
        float a0 = (cst - 0.5f * (z0 * z0 + z1 * z1 + z2 * z2 + z3 * z3)) + lpi;
        float m0a = dppMaxAll(a0);
        float u = __expf(a0 - m0a);
        float s0 = dppSumAll(u);
        double acc = (double)(m0a + __logf(s0));
        u *= (1.0f / s0);

        // m_pre ring (4-deep prefetch), wave-uniform broadcast loads
        const float* mp = m_pre + (size_t)b * T_LEN;
        float g0 = mp[1], g1 = mp[2], g2 = mp[3], g3 = mp[4];

#pragma unroll 1
        for (int t = 1; t < T_LEN; ++t) {
            float mm_c = g0; g0 = g1; g1 = g2; g2 = g3;
            int tp = t + 4; if (tp > T_LEN - 1) tp = T_LEN - 1;
            g3 = mp[tp];

            // emission t (mul path; xs reads issued early; independent of u -> overlaps)
            int o = t * 6;
            float y0 = xs[o], y1 = xs[o + 1], y2 = xs[o + 2], y3 = xs[o + 3];
            float w0 = (y0 - mu0) * i0, w1 = (y1 - mu1) * i1;
            float w2 = (y2 - mu2) * i2, w3 = (y3 - mu3) * i3;
            float lp = cst - 0.5f * (w0 * w0 + w1 * w1 + w2 * w2 + w3 * w3);
            float e_c = __expf(lp - mm_c);

            // q_j = sum_i u[i]*A[i][j] via readlane broadcast (register-only)
            float q0 = 0.f, q1 = 0.f, q2 = 0.f, q3 = 0.f;
#pragma unroll
            for (int gq = 0; gq < 4; ++gq) {
                float s[16];
#pragma unroll
                for (int m = 0; m < 16; ++m) s[m] = rl(u, 16 * gq + m);
#pragma unroll
                for (int k2 = 0; k2 < 4; ++k2) {
                    const int i = 16 * gq + 4 * k2;     // i = 4k+c, k ascending per chain
                    q0 = fmaf(s[4 * k2 + 0], Ac[i + 0], q0);
                    q1 = fmaf(s[4 * k2 + 1], Ac[i + 1], q1);
                    q2 = fmaf(s[4 * k2 + 2], Ac[i + 2], q2);
                    q3 = fmaf(s[4 * k2 + 3], Ac[i + 3], q3);
                }
            }
            u = ((q0 + q1) + (q2 + q3)) * e_c;
            acc += (double)mm_c;
            if ((t & 3) == 0) {          // deferred renorm (rounds 9/10 proven)
                float ss = dppSumAll(u);
                acc += (double)__logf(ss);
                u *= (1.0f / ss);
            }
        }
        float sf = dppSumAll(u);
        acc += (double)__logf(sf);
        if (j == 0) out[b] = (float)acc;
    } else {
        // ---------------- VITERBI: readlane broadcast + ring-8 constant-distance prefetch ----------------
        float lA[64];
        {
            const float4* g = (const float4*)lAg;
#pragma unroll
            for (int k = 0; k < 16; ++k) {
                float4 v = g[j * 16 + k];
                lA[4 * k + 0] = v.x; lA[4 * k + 1] = v.y;
                lA[4 * k + 2] = v.z; lA[4 * k + 3] = v.w;
            }
        }
        float* bb = buf + (size_t)b * T_LEN * 64 + j;

        // t = 0: seed dn, fill ring with lp rows 1..8, then overwrite row 0 with d0
        float dn = bb[0] + lpi;
        float lr[8];
#pragma unroll
        for (int i = 0; i < 8; ++i) lr[i] = bb[(size_t)(1 + i) * 64];
        bb[0] = dn;

        // main: t = 1..2040 in 255 groups of 8; ring slots are compile-time
        // indices (no shifts); load (t+8) vs store (t) distance = 2048 B, alias-free.
#pragma unroll 1
        for (int tb = 1; tb <= 2033; tb += 8) {
#pragma unroll
            for (int q = 0; q < 8; ++q) {
                const int t = tb + q;
                float lp_c = lr[q];
                lr[q] = bb[(size_t)(t + 8) * 64];   // max t+8 = 2048, in-bounds
                VIT_REDUCE(dn);
                dn = fmaxf(fmaxf(m0, m1), fmaxf(m2, m3)) + lp_c;
                bb[(size_t)t * 64] = dn;            // overwrite lp row t with d row t
            }
        }
        // row 2049 (distance >= 9 rows from last store: alias-free)
        float l_last = bb[(size_t)2049 * 64];
        // peel t = 2041..2048 from the ring (no loads)
#pragma unroll
        for (int q = 0; q < 8; ++q) {
            const int t = 2041 + q;
            float lp_c = lr[q];
            VIT_REDUCE(dn);
            dn = fmaxf(fmaxf(m0, m1), fmaxf(m2, m3)) + lp_c;
            bb[(size_t)t * 64] = dn;
        }
        // final t = 2049 (d row 2049 never read downstream: no store)
        {
            float lp_c = l_last;
            VIT_REDUCE(dn);
            dn = fmaxf(fmaxf(m0, m1), fmaxf(m2, m3)) + lp_c;
        }

        float vv = dn; int idx = j;
        waveArgmax(vv, idx);
        if (j == 0) c_last[b] = idx;
    }
}

// ===== psi recompute: persistent lA in regs, grid-stride over (t,b) pairs (round-5 verbatim) =====
extern "C" __global__ __launch_bounds__(256)
void hmm_psi(const float* __restrict__ buf,
             const float* __restrict__ lAg,
             unsigned char* __restrict__ psi)
{
    __shared__ __align__(16) float sd[4][64];
    const int warp = threadIdx.x >> 6;
    const int j = threadIdx.x & 63;
    const int wid = blockIdx.x * 4 + warp;        // 0..8191

    float lA[64];
    {
        const float4* g = (const float4*)lAg;
#pragma unroll
        for (int k = 0; k < 16; ++k) {
            float4 v = g[j * 16 + k];
            lA[4 * k + 0] = v.x; lA[4 * k + 1] = v.y;
            lA[4 * k + 2] = v.z; lA[4 * k + 3] = v.w;
        }
    }
    const float4* dv = (const float4*)sd[warp];
    const int NP = 2049 * B_SZ;

    for (int p = wid; p < NP; p += 8192) {
        const int t = (p >> 7) + 1;
        const int b = p & 127;
        float dval = buf[((size_t)b * T_LEN + (t - 1)) * 64 + j];
        sd[warp][j] = dval;    // same-wave in-order: reads below see it

        // round-5-verbatim argmax tracker (np.argmax first-occurrence semantics)
        float bv0 = -3.4e38f, bv1 = -3.4e38f, bv2 = -3.4e38f, bv3 = -3.4e38f;
        int bi0 = 0, bi1 = 1, bi2 = 2, bi3 = 3;
#pragma unroll
        for (int k = 0; k < 16; ++k) {
            float4 dd = dv[k];
            float v0 = dd.x + lA[4 * k + 0];
            float v1 = dd.y + lA[4 * k + 1];
            float v2 = dd.z + lA[4 * k + 2];
            float v3 = dd.w + lA[4 * k + 3];
            if (v0 > bv0) { bv0 = v0; bi0 = 4 * k + 0; }
            if (v1 > bv1) { bv1 = v1; bi1 = 4 * k + 1; }
            if (v2 > bv2) { bv2 = v2; bi2 = 4 * k + 2; }
            if (v3 > bv3) { bv3 = v3; bi3 = 4 * k + 3; }
        }
        float best = bv0; int bidx = bi0;
        if (bv1 > best || (bv1 == best && bi1 < bidx)) { best = bv1; bidx = bi1; }
        if (bv2 > best || (bv2 == best && bi2 < bidx)) { best = bv2; bidx = bi2; }
        if (bv3 > best || (bv3 == best && bi3 < bidx)) { best = bv3; bidx = bi3; }

        psi[((size_t)t * B_SZ + b) * 64 + j] = (unsigned char)bidx;
    }
}

// ===== backtrace: FUSED compose + bound + fill, ONE BLOCK PER BATCH.
// All data for batch b is batch-local (psi rows of b; mt, sbg in LDS), so the
// phases are separated by plain __syncthreads() — no cooperative launch, no
// cross-block ordering. Phase bodies are the round-7 proven walks
// (row-prefetch ring-8 + ds_bpermute / readlane). =====
extern "C" __global__ __launch_bounds__(256)
void hmm_btrace(const unsigned char* __restrict__ psi,
                const int* __restrict__ c_last,
                float* __restrict__ out)
{
    __shared__ int mt_s[NCHUNK][64];   // mt_s[g][j] = composed map of chunk g
    __shared__ int sbg_s[NCHUNK];      // sbg_s[g]   = state at t = 64*g

    const int b    = blockIdx.x;
    const int warp = threadIdx.x >> 6;
    const int j    = threadIdx.x & 63;
    const int cl   = c_last[b];

    // ---------------- phase A: per-chunk compose (ds_bpermute walk) ----------------
    for (int g = warp; g < NCHUNK; g += 4) {
        const int e  = (g < NCHUNK - 1) ? g * 64 + 64 : (T_LEN - 1);
        const int t0 = g * 64 + 1;
        int M = j;
        int r[8];
#pragma unroll
        for (int i = 0; i < 8; ++i) {
            int t = e - i;
            r[i] = (t >= t0) ? (int)psi[((size_t)t * B_SZ + b) * 64 + j] : 0;
        }
#pragma unroll 1
        for (int t = e; t >= t0; --t) {
            const int q = (e - t) & 7;
            int row = r[q];
            int tn = t - 8;
            r[q] = (tn >= t0) ? (int)psi[((size_t)tn * B_SZ + b) * 64 + j] : 0;
            M = __builtin_amdgcn_ds_bpermute(M << 2, row);   // M = row[M], per lane
        }
        mt_s[g][j] = M;
    }
    __syncthreads();

    // ---------------- phase B: boundary walk (wave 0, readlane) ----------------
    if (warp == 0) {
        int rows[NCHUNK];
#pragma unroll
        for (int q = 0; q < NCHUNK; ++q) rows[q] = mt_s[q][j];
        int cur = cl;
#pragma unroll
        for (int q = NCHUNK - 1; q >= 0; --q) {
            cur = __builtin_amdgcn_readlane(rows[q], cur);   // cur = mt_s[q][cur]
            if (j == 0) sbg_s[q] = cur;
        }
    }
    __syncthreads();

    // ---------------- phase C: chunk fill (readlane walk, psi ring-8) ----------------
    float* oc = out + B_SZ + (size_t)b * T_LEN;
    for (int g = warp; g < NCHUNK; g += 4) {
        const int e  = (g < NCHUNK - 1) ? g * 64 + 64 : (T_LEN - 1);
        const int t0 = g * 64 + 1;
        int s = (g < NCHUNK - 1) ? sbg_s[g + 1] : cl;
        if (g == NCHUNK - 1 && j == 0) oc[T_LEN - 1] = (float)cl;

        int r[8];
#pragma unroll
        for (int i = 0; i < 8; ++i) {
            int t = e - i;
            r[i] = (t >= t0) ? (int)psi[((size_t)t * B_SZ + b) * 64 + j] : 0;
        }
#pragma unroll 1
        for (int t = e; t >= t0; --t) {
            const int q = (e - t) & 7;
            int row = r[q];
            int tn = t - 8;
            r[q] = (tn >= t0) ? (int)psi[((size_t)tn * B_SZ + b) * 64 + j] : 0;
            s = __builtin_amdgcn_readlane(row, s);           // s = psi_row_t[s]
            if (j == 0) oc[t - 1] = (float)s;
        }
    }
}

extern "C" void kernel_launch(void* const* d_in, const int* in_sizes, int n_in,
                              void* d_out, int out_size, void* d_ws, size_t ws_size,
                              hipStream_t stream)
{
    const float* x      = (const float*)d_in[0];
    const float* means  = (const float*)d_in[1];
    const float* stds   = (const float*)d_in[2];
    const float* logA   = (const float*)d_in[3];
    const float* logpi  = (const float*)d_in[4];
    float* out = (float*)d_out;

    // workspace layout (mt/sbg now live in LDS of hmm_btrace):
    // m_pre overlaps the psi region (consumed by hmm_main before hmm_psi writes psi).
    char* base = (char*)d_ws;
    float*         buf   = (float*)base;                                 // 67,174,400 (lp then d, in place)
    unsigned char* psi   = (unsigned char*)(base + 67174400);            // 16,793,600
    float*         m_pre = (float*)(base + 67174400);                    //  1,049,600 (dead after hmm_main)
    int*           cl    = (int*)(base + 84238336);                      //        512
    float*         lAg   = (float*)(base + 84238848);                    //     16,384
    float*         lpig  = (float*)(base + 84255232);                    //        256

    hipLaunchKernelGGL(hmm_emis, dim3((T_LEN * B_SZ) / 4), dim3(256), 0, stream,
                       x, means, stds, buf, m_pre, logA, logpi, lAg, lpig);
    hipLaunchKernelGGL(hmm_main, dim3(2 * B_SZ), dim3(64), 0, stream,
                       x, means, stds, lAg, lpig, out, buf, m_pre, cl);
    hipLaunchKernelGGL(hmm_psi, dim3(2048), dim3(256), 0, stream, buf, lAg, psi);
    hipLaunchKernelGGL(hmm_btrace, dim3(B_SZ), dim3(256), 0, stream, psi, cl, out);
}

// Round 10
// 1009.815 us; speedup vs baseline: 1.2599x; 1.2535x over previous
//
#include <hip/hip_runtime.h>

#define T_LEN 2050
#define B_SZ 128
#define NCHUNK 33               // chunks of steps t=1..2049
#define HL2PI 0.91893853320467274178f

// ---------- wave-wide helpers (wave = 64 lanes) ----------
__device__ __forceinline__ float waveMax(float v) {
#pragma unroll
    for (int off = 32; off >= 1; off >>= 1)
        v = fmaxf(v, __shfl_xor(v, off, 64));
    return v;
}
__device__ __forceinline__ float waveSum(float v) {
#pragma unroll
    for (int off = 32; off >= 1; off >>= 1)
        v += __shfl_xor(v, off, 64);
    return v;
}
__device__ __forceinline__ void waveArgmax(float& v, int& idx) {
#pragma unroll
    for (int off = 32; off >= 1; off >>= 1) {
        float ov = __shfl_xor(v, off, 64);
        int   oi = __shfl_xor(idx, off, 64);
        if (ov > v || (ov == v && oi < idx)) { v = ov; idx = oi; }
    }
}
__device__ __forceinline__ void cfence() { asm volatile("" ::: "memory"); }

// register-only broadcast: lane i's value -> SGPR (uniform), zero memory latency
__device__ __forceinline__ float rl(float v, int lane) {
    return __int_as_float(__builtin_amdgcn_readlane(__float_as_int(v), lane));
}

// DPP full-wave reductions (rounds 5-10 proven)
__device__ __forceinline__ float dppSumAll(float v) {
#define SSTEP(ctrl) { int t_ = __builtin_amdgcn_update_dpp(0, __float_as_int(v), ctrl, 0xf, 0xf, true); \
                      v = v + __int_as_float(t_); }
    SSTEP(0x111) SSTEP(0x112) SSTEP(0x114) SSTEP(0x118) SSTEP(0x142) SSTEP(0x143)
#undef SSTEP
    return __int_as_float(__builtin_amdgcn_readlane(__float_as_int(v), 63));
}
__device__ __forceinline__ float dppMaxAll(float v) {
#define MSTEP(ctrl) { int t_ = __builtin_amdgcn_update_dpp(__float_as_int(v), __float_as_int(v), ctrl, 0xf, 0xf, false); \
                      v = fmaxf(v, __int_as_float(t_)); }
    MSTEP(0x111) MSTEP(0x112) MSTEP(0x114) MSTEP(0x118) MSTEP(0x142) MSTEP(0x143)
#undef MSTEP
    return __int_as_float(__builtin_amdgcn_readlane(__float_as_int(v), 63));
}

// ===== emission precompute (EXACT op order, round-2 proven bit-exact) -> buf[b][t][64], m_pre[b][t]
// + FUSED prep (block 0, wave 0, same-wave in-order DS — round-9 validated absmax 0.0):
// log_softmax(log_A) -> lAg column-major, log_softmax(log_pi). =====
extern "C" __global__ __launch_bounds__(256)
void hmm_emis(const float* __restrict__ x,
              const float* __restrict__ means,
              const float* __restrict__ stds,
              float* __restrict__ buf,
              float* __restrict__ m_pre,
              const float* __restrict__ logA_in,
              const float* __restrict__ logpi_in,
              float* __restrict__ lAg,
              float* __restrict__ lpig)
{
    __shared__ float la[64 * 65];
    __shared__ float rowlse[64];

    const int wid = blockIdx.x * 4 + (threadIdx.x >> 6);
    const int j = threadIdx.x & 63;
    const int t = wid >> 7;          // wid = t*128 + b
    const int b = wid & 127;

    const float* xt = x + ((size_t)b * T_LEN + t) * 6;
    float x0 = xt[0], x1 = xt[1], x2 = xt[2], x3 = xt[3];

    float mu0 = means[j * 6 + 0], mu1 = means[j * 6 + 1];
    float mu2 = means[j * 6 + 2], mu3 = means[j * 6 + 3];
    float sg0 = fmaxf(stds[j * 6 + 0], 0.f) + 0.1f;
    float sg1 = fmaxf(stds[j * 6 + 1], 0.f) + 0.1f;
    float sg2 = fmaxf(stds[j * 6 + 2], 0.f) + 0.1f;
    float sg3 = fmaxf(stds[j * 6 + 3], 0.f) + 0.1f;
    float ls0 = logf(sg0), ls1 = logf(sg1), ls2 = logf(sg2), ls3 = logf(sg3);

    float z0 = (x0 - mu0) / sg0, z1 = (x1 - mu1) / sg1;
    float z2 = (x2 - mu2) / sg2, z3 = (x3 - mu3) / sg3;
    float e0 = ((-0.5f * z0) * z0 - ls0) - HL2PI;
    float e1 = ((-0.5f * z1) * z1 - ls1) - HL2PI;
    float e2 = ((-0.5f * z2) * z2 - ls2) - HL2PI;
    float e3 = ((-0.5f * z3) * z3 - ls3) - HL2PI;
    float lp = ((e0 + e1) + e2) + e3;

    buf[((size_t)b * T_LEN + t) * 64 + j] = lp;
    float mm = waveMax(lp);
    if (j == 0) m_pre[(size_t)b * T_LEN + t] = mm;

    // ---- fused prep: block 0, wave 0 only (exact op order, rounds 1..10 proven) ----
    if (blockIdx.x == 0 && threadIdx.x < 64) {
#pragma unroll
        for (int k = 0; k < 64; ++k)
            la[k * 65 + j] = logA_in[k * 64 + j];
        cfence();
        {
            float m = -1e30f;
#pragma unroll
            for (int k = 0; k < 64; ++k) m = fmaxf(m, la[j * 65 + k]);
            float s = 0.f;
#pragma unroll
            for (int k = 0; k < 64; ++k) s += expf(la[j * 65 + k] - m);
            rowlse[j] = m + logf(s);
        }
        cfence();
        {
            float v = logpi_in[j];
            float m = waveMax(v);
            float s = waveSum(expf(v - m));
            lpig[j] = v - (m + logf(s));
        }
        float4* o = (float4*)lAg;
#pragma unroll
        for (int k = 0; k < 16; ++k) {
            float4 v;
            v.x = la[(4 * k + 0) * 65 + j] - rowlse[4 * k + 0];
            v.y = la[(4 * k + 1) * 65 + j] - rowlse[4 * k + 1];
            v.z = la[(4 * k + 2) * 65 + j] - rowlse[4 * k + 2];
            v.w = la[(4 * k + 3) * 65 + j] - rowlse[4 * k + 3];
            o[j * 16 + k] = v;
        }
    }
}

// viterbi reduce: adds elementwise-exact, fmax exactly assoc/comm (max3-fusable)
#define VIT_REDUCE(SRC)                                                   \
    float m0 = -3.4e38f, m1 = -3.4e38f, m2 = -3.4e38f, m3 = -3.4e38f;     \
    _Pragma("unroll")                                                     \
    for (int gq = 0; gq < 4; ++gq) {                                      \
        float s_[16];                                                     \
        _Pragma("unroll")                                                 \
        for (int m_ = 0; m_ < 16; ++m_) s_[m_] = rl((SRC), 16 * gq + m_); \
        __builtin_amdgcn_sched_barrier(0);                                \
        _Pragma("unroll")                                                 \
        for (int k2 = 0; k2 < 4; k2 += 2) {                               \
            const int ia = 16 * gq + 4 * k2;                              \
            const int ib = ia + 4;                                        \
            float a0_ = s_[4*k2+0] + lA[ia+0], b0_ = s_[4*k2+4] + lA[ib+0]; \
            float a1_ = s_[4*k2+1] + lA[ia+1], b1_ = s_[4*k2+5] + lA[ib+1]; \
            float a2_ = s_[4*k2+2] + lA[ia+2], b2_ = s_[4*k2+6] + lA[ib+2]; \
            float a3_ = s_[4*k2+3] + lA[ia+3], b3_ = s_[4*k2+7] + lA[ib+3]; \
            m0 = fmaxf(fmaxf(m0, a0_), b0_);                              \
            m1 = fmaxf(fmaxf(m1, a1_), b1_);                              \
            m2 = fmaxf(fmaxf(m2, a2_), b2_);                              \
            m3 = fmaxf(fmaxf(m3, a3_), b3_);                              \
        }                                                                 \
    }

// ===== main: single wave per chain (round-5 proven structure, byte-identical).
// blocks 0..127: forward -> out[b]; blocks 128..255: viterbi -> d in buf, c_last =====
extern "C" __global__ __launch_bounds__(64, 1)
void hmm_main(const float* __restrict__ x,
              const float* __restrict__ means,
              const float* __restrict__ stds,
              const float* __restrict__ lAg,
              const float* __restrict__ lpig,
              float* __restrict__ out,
              float* __restrict__ buf,
              const float* __restrict__ m_pre,
              int* __restrict__ c_last)
{
    __shared__ __align__(16) float xs[12304];     // x[b] (forward half only)

    const int j   = threadIdx.x;
    const int bid = blockIdx.x;
    const bool is_fwd = (bid < B_SZ);
    const int b = is_fwd ? bid : bid - B_SZ;

    float lpi = lpig[j];

    if (is_fwd) {
        // stage x (inline mul-path emissions — rounds 5-9 proven)
        {
            const float4* xg4 = (const float4*)(x + (size_t)b * T_LEN * 6);
            float4* xs4 = (float4*)xs;
            for (int i = j; i < 3075; i += 64) xs4[i] = xg4[i];
        }
        float mu0 = means[j * 6 + 0], mu1 = means[j * 6 + 1];
        float mu2 = means[j * 6 + 2], mu3 = means[j * 6 + 3];
        float sg0 = fmaxf(stds[j * 6 + 0], 0.f) + 0.1f;
        float sg1 = fmaxf(stds[j * 6 + 1], 0.f) + 0.1f;
        float sg2 = fmaxf(stds[j * 6 + 2], 0.f) + 0.1f;
        float sg3 = fmaxf(stds[j * 6 + 3], 0.f) + 0.1f;
        float ls0 = logf(sg0), ls1 = logf(sg1), ls2 = logf(sg2), ls3 = logf(sg3);
        float i0 = 1.f / sg0, i1 = 1.f / sg1, i2 = 1.f / sg2, i3 = 1.f / sg3;
        float cst = -(ls0 + ls1 + ls2 + ls3) - 4.f * HL2PI;

        float Ac[64];
        {
            const float4* g = (const float4*)lAg;
#pragma unroll
            for (int k = 0; k < 16; ++k) {
                float4 v = g[j * 16 + k];
                Ac[4 * k + 0] = __expf(v.x); Ac[4 * k + 1] = __expf(v.y);
                Ac[4 * k + 2] = __expf(v.z); Ac[4 * k + 3] = __expf(v.w);
            }
        }
        cfence();   // xs staged (same-wave in-order DS)

        // t = 0
        float z0 = (xs[0] - mu0) * i0, z1 = (xs[1] - mu1) * i1;
        float z2 = (xs[2] - mu2) * i2, z3 = (xs[3] - mu3) * i3;
        float a0 = (cst - 0.5f * (z0 * z0 + z1 * z1 + z2 * z2 + z3 * z3)) + lpi;
        float m0a = dppMaxAll(a0);
        float u = __expf(a0 - m0a);
        float s0 = dppSumAll(u);
        double acc = (double)(m0a + __logf(s0));
        u *= (1.0f / s0);

        // m_pre ring (4-deep prefetch), wave-uniform broadcast loads
        const float* mp = m_pre + (size_t)b * T_LEN;
        float g0 = mp[1], g1 = mp[2], g2 = mp[3], g3 = mp[4];

#pragma unroll 1
        for (int t = 1; t < T_LEN; ++t) {
            float mm_c = g0; g0 = g1; g1 = g2; g2 = g3;
            int tp = t + 4; if (tp > T_LEN - 1) tp = T_LEN - 1;
            g3 = mp[tp];

            // emission t (mul path; xs reads issued early; independent of u -> overlaps)
            int o = t * 6;
            float y0 = xs[o], y1 = xs[o + 1], y2 = xs[o + 2], y3 = xs[o + 3];
            float w0 = (y0 - mu0) * i0, w1 = (y1 - mu1) * i1;
            float w2 = (y2 - mu2) * i2, w3 = (y3 - mu3) * i3;
            float lp = cst - 0.5f * (w0 * w0 + w1 * w1 + w2 * w2 + w3 * w3);
            float e_c = __expf(lp - mm_c);

            // q_j = sum_i u[i]*A[i][j] via readlane broadcast (register-only)
            float q0 = 0.f, q1 = 0.f, q2 = 0.f, q3 = 0.f;
#pragma unroll
            for (int gq = 0; gq < 4; ++gq) {
                float s[16];
#pragma unroll
                for (int m = 0; m < 16; ++m) s[m] = rl(u, 16 * gq + m);
#pragma unroll
                for (int k2 = 0; k2 < 4; ++k2) {
                    const int i = 16 * gq + 4 * k2;     // i = 4k+c, k ascending per chain
                    q0 = fmaf(s[4 * k2 + 0], Ac[i + 0], q0);
                    q1 = fmaf(s[4 * k2 + 1], Ac[i + 1], q1);
                    q2 = fmaf(s[4 * k2 + 2], Ac[i + 2], q2);
                    q3 = fmaf(s[4 * k2 + 3], Ac[i + 3], q3);
                }
            }
            u = ((q0 + q1) + (q2 + q3)) * e_c;
            acc += (double)mm_c;
            if ((t & 3) == 0) {          // deferred renorm (rounds 9/10 proven)
                float ss = dppSumAll(u);
                acc += (double)__logf(ss);
                u *= (1.0f / ss);
            }
        }
        float sf = dppSumAll(u);
        acc += (double)__logf(sf);
        if (j == 0) out[b] = (float)acc;
    } else {
        // ---------------- VITERBI: readlane broadcast + ring-8 constant-distance prefetch ----------------
        float lA[64];
        {
            const float4* g = (const float4*)lAg;
#pragma unroll
            for (int k = 0; k < 16; ++k) {
                float4 v = g[j * 16 + k];
                lA[4 * k + 0] = v.x; lA[4 * k + 1] = v.y;
                lA[4 * k + 2] = v.z; lA[4 * k + 3] = v.w;
            }
        }
        float* bb = buf + (size_t)b * T_LEN * 64 + j;

        // t = 0: seed dn, fill ring with lp rows 1..8, then overwrite row 0 with d0
        float dn = bb[0] + lpi;
        float lr[8];
#pragma unroll
        for (int i = 0; i < 8; ++i) lr[i] = bb[(size_t)(1 + i) * 64];
        bb[0] = dn;

        // main: t = 1..2040 in 255 groups of 8; ring slots are compile-time
        // indices (no shifts); load (t+8) vs store (t) distance = 2048 B, alias-free.
#pragma unroll 1
        for (int tb = 1; tb <= 2033; tb += 8) {
#pragma unroll
            for (int q = 0; q < 8; ++q) {
                const int t = tb + q;
                float lp_c = lr[q];
                lr[q] = bb[(size_t)(t + 8) * 64];   // max t+8 = 2048, in-bounds
                VIT_REDUCE(dn);
                dn = fmaxf(fmaxf(m0, m1), fmaxf(m2, m3)) + lp_c;
                bb[(size_t)t * 64] = dn;            // overwrite lp row t with d row t
            }
        }
        // row 2049 (distance >= 9 rows from last store: alias-free)
        float l_last = bb[(size_t)2049 * 64];
        // peel t = 2041..2048 from the ring (no loads)
#pragma unroll
        for (int q = 0; q < 8; ++q) {
            const int t = 2041 + q;
            float lp_c = lr[q];
            VIT_REDUCE(dn);
            dn = fmaxf(fmaxf(m0, m1), fmaxf(m2, m3)) + lp_c;
            bb[(size_t)t * 64] = dn;
        }
        // final t = 2049 (d row 2049 never read downstream: no store)
        {
            float lp_c = l_last;
            VIT_REDUCE(dn);
            dn = fmaxf(fmaxf(m0, m1), fmaxf(m2, m3)) + lp_c;
        }

        float vv = dn; int idx = j;
        waveArgmax(vv, idx);
        if (j == 0) c_last[b] = idx;
    }
}

// ===== FUSED psi + compose: one wave per (b, g) chunk (4224 waves — same
// parallelism as the round-5 compose). Each wave: (a) round-5-verbatim argmax
// tracker over its chunk's 64 d-rows -> psi rows, stored to global AND into a
// per-wave LDS slot; (b) compose chase through the LDS copy (sequential u8
// reads, ~60 cyc/step vs ~500 global; NO runtime-indexed register arrays);
// (c) mt store. Identical bytes/order as psi-then-compose. =====
extern "C" __global__ __launch_bounds__(256)
void hmm_pscomp(const float* __restrict__ buf,
                const float* __restrict__ lAg,
                unsigned char* __restrict__ psi,
                unsigned char* __restrict__ mt)
{
    __shared__ __align__(16) float sd[4][64];
    __shared__ unsigned char prow[4][64][64];     // per-wave psi rows of this chunk

    const int warp = threadIdx.x >> 6;
    const int j = threadIdx.x & 63;
    const int w = blockIdx.x * 4 + warp;          // 0..4223
    const int g = w % NCHUNK;
    const int b = w / NCHUNK;
    const int t0 = g * 64 + 1;
    const int e  = (g < NCHUNK - 1) ? g * 64 + 64 : (T_LEN - 1);

    float lA[64];
    {
        const float4* gp = (const float4*)lAg;
#pragma unroll
        for (int k = 0; k < 16; ++k) {
            float4 v = gp[j * 16 + k];
            lA[4 * k + 0] = v.x; lA[4 * k + 1] = v.y;
            lA[4 * k + 2] = v.z; lA[4 * k + 3] = v.w;
        }
    }
    const float4* dv = (const float4*)sd[warp];

#pragma unroll 1
    for (int t = t0; t <= e; ++t) {
        float dval = buf[((size_t)b * T_LEN + (t - 1)) * 64 + j];
        sd[warp][j] = dval;    // same-wave in-order: reads below see it

        // round-5-verbatim argmax tracker (np.argmax first-occurrence semantics)
        float bv0 = -3.4e38f, bv1 = -3.4e38f, bv2 = -3.4e38f, bv3 = -3.4e38f;
        int bi0 = 0, bi1 = 1, bi2 = 2, bi3 = 3;
#pragma unroll
        for (int k = 0; k < 16; ++k) {
            float4 dd = dv[k];
            float v0 = dd.x + lA[4 * k + 0];
            float v1 = dd.y + lA[4 * k + 1];
            float v2 = dd.z + lA[4 * k + 2];
            float v3 = dd.w + lA[4 * k + 3];
            if (v0 > bv0) { bv0 = v0; bi0 = 4 * k + 0; }
            if (v1 > bv1) { bv1 = v1; bi1 = 4 * k + 1; }
            if (v2 > bv2) { bv2 = v2; bi2 = 4 * k + 2; }
            if (v3 > bv3) { bv3 = v3; bi3 = 4 * k + 3; }
        }
        float best = bv0; int bidx = bi0;
        if (bv1 > best || (bv1 == best && bi1 < bidx)) { best = bv1; bidx = bi1; }
        if (bv2 > best || (bv2 == best && bi2 < bidx)) { best = bv2; bidx = bi2; }
        if (bv3 > best || (bv3 == best && bi3 < bidx)) { best = bv3; bidx = bi3; }

        psi[((size_t)t * B_SZ + b) * 64 + j] = (unsigned char)bidx;
        prow[warp][t - t0][j] = (unsigned char)bidx;
    }

    // compose chase through LDS copy (same-wave in-order DS; per-lane M)
    int M = j;
#pragma unroll 1
    for (int tr = e - t0; tr >= 0; --tr)
        M = (int)prow[warp][tr][M];               // M = psi_row_t[M]
    mt[((size_t)g * B_SZ + b) * 64 + j] = (unsigned char)M;
}

// ===== boundary walk + parallel chunk fill: block per batch (round-5 verbatim) =====
extern "C" __global__ __launch_bounds__(64, 1)
void hmm_fill(const unsigned char* __restrict__ psi,
              const unsigned char* __restrict__ mt,
              const int* __restrict__ c_last,
              float* __restrict__ out)
{
    __shared__ int sb[NCHUNK];       // sb[g] = state at t = 64*g
    const int b = blockIdx.x;
    const int g = threadIdx.x;
    const int cl = c_last[b];
    if (g == 0) {
        int cur = cl;
        for (int q = NCHUNK - 1; q >= 0; --q) {
            cur = mt[((size_t)q * B_SZ + b) * 64 + cur];
            sb[q] = cur;
        }
    }
    cfence();   // single wave, in-order DS
    float* oc = out + B_SZ + (size_t)b * T_LEN;
    if (g == NCHUNK) {
        oc[T_LEN - 1] = (float)cl;
    } else if (g < NCHUNK) {
        const int e = (g < NCHUNK - 1) ? g * 64 + 64 : (T_LEN - 1);
        int s = (g < NCHUNK - 1) ? sb[g + 1] : cl;
        for (int t = e; t >= g * 64 + 1; --t) {
            s = psi[((size_t)t * B_SZ + b) * 64 + s];
            oc[t - 1] = (float)s;
        }
    }
}

extern "C" void kernel_launch(void* const* d_in, const int* in_sizes, int n_in,
                              void* d_out, int out_size, void* d_ws, size_t ws_size,
                              hipStream_t stream)
{
    const float* x      = (const float*)d_in[0];
    const float* means  = (const float*)d_in[1];
    const float* stds   = (const float*)d_in[2];
    const float* logA   = (const float*)d_in[3];
    const float* logpi  = (const float*)d_in[4];
    float* out = (float*)d_out;

    // workspace: m_pre overlaps psi region (consumed by hmm_main before hmm_pscomp writes psi)
    char* base = (char*)d_ws;
    float*         buf   = (float*)base;                                 // 67,174,400 (lp then d, in place)
    unsigned char* psi   = (unsigned char*)(base + 67174400);            // 16,793,600
    float*         m_pre = (float*)(base + 67174400);                    //  1,049,600 (dead after hmm_main)
    unsigned char* mt    = (unsigned char*)(base + 83968000);            //    270,336
    int*           cl    = (int*)(base + 84238336);                      //        512
    float*         lAg   = (float*)(base + 84238848);                    //     16,384
    float*         lpig  = (float*)(base + 84255232);                    //        256

    hipLaunchKernelGGL(hmm_emis, dim3((T_LEN * B_SZ) / 4), dim3(256), 0, stream,
                       x, means, stds, buf, m_pre, logA, logpi, lAg, lpig);
    hipLaunchKernelGGL(hmm_main, dim3(2 * B_SZ), dim3(64), 0, stream,
                       x, means, stds, lAg, lpig, out, buf, m_pre, cl);
    hipLaunchKernelGGL(hmm_pscomp, dim3((NCHUNK * B_SZ) / 4), dim3(256), 0, stream,
                       buf, lAg, psi, mt);
    hipLaunchKernelGGL(hmm_fill, dim3(B_SZ), dim3(64), 0, stream, psi, mt, cl, out);
}

// Round 11
// 998.625 us; speedup vs baseline: 1.2741x; 1.0112x over previous
//
#include <hip/hip_runtime.h>

#define T_LEN 2050
#define B_SZ 128
#define NCHUNK 33               // chunks of steps t=1..2049
#define HL2PI 0.91893853320467274178f

// ---------- wave-wide helpers (wave = 64 lanes) ----------
__device__ __forceinline__ float waveMax(float v) {
#pragma unroll
    for (int off = 32; off >= 1; off >>= 1)
        v = fmaxf(v, __shfl_xor(v, off, 64));
    return v;
}
__device__ __forceinline__ float waveSum(float v) {
#pragma unroll
    for (int off = 32; off >= 1; off >>= 1)
        v += __shfl_xor(v, off, 64);
    return v;
}
__device__ __forceinline__ void waveArgmax(float& v, int& idx) {
#pragma unroll
    for (int off = 32; off >= 1; off >>= 1) {
        float ov = __shfl_xor(v, off, 64);
        int   oi = __shfl_xor(idx, off, 64);
        if (ov > v || (ov == v && oi < idx)) { v = ov; idx = oi; }
    }
}
__device__ __forceinline__ void cfence() { asm volatile("" ::: "memory"); }

// register-only broadcast: lane i's value -> SGPR (uniform), zero memory latency
__device__ __forceinline__ float rl(float v, int lane) {
    return __int_as_float(__builtin_amdgcn_readlane(__float_as_int(v), lane));
}

// DPP full-wave reductions (rounds 5-10 proven)
__device__ __forceinline__ float dppSumAll(float v) {
#define SSTEP(ctrl) { int t_ = __builtin_amdgcn_update_dpp(0, __float_as_int(v), ctrl, 0xf, 0xf, true); \
                      v = v + __int_as_float(t_); }
    SSTEP(0x111) SSTEP(0x112) SSTEP(0x114) SSTEP(0x118) SSTEP(0x142) SSTEP(0x143)
#undef SSTEP
    return __int_as_float(__builtin_amdgcn_readlane(__float_as_int(v), 63));
}
__device__ __forceinline__ float dppMaxAll(float v) {
#define MSTEP(ctrl) { int t_ = __builtin_amdgcn_update_dpp(__float_as_int(v), __float_as_int(v), ctrl, 0xf, 0xf, false); \
                      v = fmaxf(v, __int_as_float(t_)); }
    MSTEP(0x111) MSTEP(0x112) MSTEP(0x114) MSTEP(0x118) MSTEP(0x142) MSTEP(0x143)
#undef MSTEP
    return __int_as_float(__builtin_amdgcn_readlane(__float_as_int(v), 63));
}

// ===== emission precompute (EXACT op order, round-2 proven bit-exact) -> buf[b][t][64], m_pre[b][t]
// + FUSED prep (block 0, wave 0, same-wave in-order DS — rounds 9/10 validated absmax 0.0):
// log_softmax(log_A) -> lAg column-major, log_softmax(log_pi). =====
extern "C" __global__ __launch_bounds__(256)
void hmm_emis(const float* __restrict__ x,
              const float* __restrict__ means,
              const float* __restrict__ stds,
              float* __restrict__ buf,
              float* __restrict__ m_pre,
              const float* __restrict__ logA_in,
              const float* __restrict__ logpi_in,
              float* __restrict__ lAg,
              float* __restrict__ lpig)
{
    __shared__ float la[64 * 65];
    __shared__ float rowlse[64];

    const int wid = blockIdx.x * 4 + (threadIdx.x >> 6);
    const int j = threadIdx.x & 63;
    const int t = wid >> 7;          // wid = t*128 + b
    const int b = wid & 127;

    const float* xt = x + ((size_t)b * T_LEN + t) * 6;
    float x0 = xt[0], x1 = xt[1], x2 = xt[2], x3 = xt[3];

    float mu0 = means[j * 6 + 0], mu1 = means[j * 6 + 1];
    float mu2 = means[j * 6 + 2], mu3 = means[j * 6 + 3];
    float sg0 = fmaxf(stds[j * 6 + 0], 0.f) + 0.1f;
    float sg1 = fmaxf(stds[j * 6 + 1], 0.f) + 0.1f;
    float sg2 = fmaxf(stds[j * 6 + 2], 0.f) + 0.1f;
    float sg3 = fmaxf(stds[j * 6 + 3], 0.f) + 0.1f;
    float ls0 = logf(sg0), ls1 = logf(sg1), ls2 = logf(sg2), ls3 = logf(sg3);

    float z0 = (x0 - mu0) / sg0, z1 = (x1 - mu1) / sg1;
    float z2 = (x2 - mu2) / sg2, z3 = (x3 - mu3) / sg3;
    float e0 = ((-0.5f * z0) * z0 - ls0) - HL2PI;
    float e1 = ((-0.5f * z1) * z1 - ls1) - HL2PI;
    float e2 = ((-0.5f * z2) * z2 - ls2) - HL2PI;
    float e3 = ((-0.5f * z3) * z3 - ls3) - HL2PI;
    float lp = ((e0 + e1) + e2) + e3;

    buf[((size_t)b * T_LEN + t) * 64 + j] = lp;
    float mm = waveMax(lp);
    if (j == 0) m_pre[(size_t)b * T_LEN + t] = mm;

    // ---- fused prep: block 0, wave 0 only (exact op order, rounds 1..10 proven) ----
    if (blockIdx.x == 0 && threadIdx.x < 64) {
#pragma unroll
        for (int k = 0; k < 64; ++k)
            la[k * 65 + j] = logA_in[k * 64 + j];
        cfence();
        {
            float m = -1e30f;
#pragma unroll
            for (int k = 0; k < 64; ++k) m = fmaxf(m, la[j * 65 + k]);
            float s = 0.f;
#pragma unroll
            for (int k = 0; k < 64; ++k) s += expf(la[j * 65 + k] - m);
            rowlse[j] = m + logf(s);
        }
        cfence();
        {
            float v = logpi_in[j];
            float m = waveMax(v);
            float s = waveSum(expf(v - m));
            lpig[j] = v - (m + logf(s));
        }
        float4* o = (float4*)lAg;
#pragma unroll
        for (int k = 0; k < 16; ++k) {
            float4 v;
            v.x = la[(4 * k + 0) * 65 + j] - rowlse[4 * k + 0];
            v.y = la[(4 * k + 1) * 65 + j] - rowlse[4 * k + 1];
            v.z = la[(4 * k + 2) * 65 + j] - rowlse[4 * k + 2];
            v.w = la[(4 * k + 3) * 65 + j] - rowlse[4 * k + 3];
            o[j * 16 + k] = v;
        }
    }
}

// viterbi reduce: adds elementwise-exact, fmax exactly assoc/comm (max3-fusable)
#define VIT_REDUCE(SRC)                                                   \
    float m0 = -3.4e38f, m1 = -3.4e38f, m2 = -3.4e38f, m3 = -3.4e38f;     \
    _Pragma("unroll")                                                     \
    for (int gq = 0; gq < 4; ++gq) {                                      \
        float s_[16];                                                     \
        _Pragma("unroll")                                                 \
        for (int m_ = 0; m_ < 16; ++m_) s_[m_] = rl((SRC), 16 * gq + m_); \
        __builtin_amdgcn_sched_barrier(0);                                \
        _Pragma("unroll")                                                 \
        for (int k2 = 0; k2 < 4; k2 += 2) {                               \
            const int ia = 16 * gq + 4 * k2;                              \
            const int ib = ia + 4;                                        \
            float a0_ = s_[4*k2+0] + lA[ia+0], b0_ = s_[4*k2+4] + lA[ib+0]; \
            float a1_ = s_[4*k2+1] + lA[ia+1], b1_ = s_[4*k2+5] + lA[ib+1]; \
            float a2_ = s_[4*k2+2] + lA[ia+2], b2_ = s_[4*k2+6] + lA[ib+2]; \
            float a3_ = s_[4*k2+3] + lA[ia+3], b3_ = s_[4*k2+7] + lA[ib+3]; \
            m0 = fmaxf(fmaxf(m0, a0_), b0_);                              \
            m1 = fmaxf(fmaxf(m1, a1_), b1_);                              \
            m2 = fmaxf(fmaxf(m2, a2_), b2_);                              \
            m3 = fmaxf(fmaxf(m3, a3_), b3_);                              \
        }                                                                 \
    }

// ===== main: single wave per chain (round-5 proven structure, byte-identical).
// blocks 0..127: forward -> out[b]; blocks 128..255: viterbi -> d in buf, c_last =====
extern "C" __global__ __launch_bounds__(64, 1)
void hmm_main(const float* __restrict__ x,
              const float* __restrict__ means,
              const float* __restrict__ stds,
              const float* __restrict__ lAg,
              const float* __restrict__ lpig,
              float* __restrict__ out,
              float* __restrict__ buf,
              const float* __restrict__ m_pre,
              int* __restrict__ c_last)
{
    __shared__ __align__(16) float xs[12304];     // x[b] (forward half only)

    const int j   = threadIdx.x;
    const int bid = blockIdx.x;
    const bool is_fwd = (bid < B_SZ);
    const int b = is_fwd ? bid : bid - B_SZ;

    float lpi = lpig[j];

    if (is_fwd) {
        // stage x (inline mul-path emissions — rounds 5-9 proven)
        {
            const float4* xg4 = (const float4*)(x + (size_t)b * T_LEN * 6);
            float4* xs4 = (float4*)xs;
            for (int i = j; i < 3075; i += 64) xs4[i] = xg4[i];
        }
        float mu0 = means[j * 6 + 0], mu1 = means[j * 6 + 1];
        float mu2 = means[j * 6 + 2], mu3 = means[j * 6 + 3];
        float sg0 = fmaxf(stds[j * 6 + 0], 0.f) + 0.1f;
        float sg1 = fmaxf(stds[j * 6 + 1], 0.f) + 0.1f;
        float sg2 = fmaxf(stds[j * 6 + 2], 0.f) + 0.1f;
        float sg3 = fmaxf(stds[j * 6 + 3], 0.f) + 0.1f;
        float ls0 = logf(sg0), ls1 = logf(sg1), ls2 = logf(sg2), ls3 = logf(sg3);
        float i0 = 1.f / sg0, i1 = 1.f / sg1, i2 = 1.f / sg2, i3 = 1.f / sg3;
        float cst = -(ls0 + ls1 + ls2 + ls3) - 4.f * HL2PI;

        float Ac[64];
        {
            const float4* g = (const float4*)lAg;
#pragma unroll
            for (int k = 0; k < 16; ++k) {
                float4 v = g[j * 16 + k];
                Ac[4 * k + 0] = __expf(v.x); Ac[4 * k + 1] = __expf(v.y);
                Ac[4 * k + 2] = __expf(v.z); Ac[4 * k + 3] = __expf(v.w);
            }
        }
        cfence();   // xs staged (same-wave in-order DS)

        // t = 0
        float z0 = (xs[0] - mu0) * i0, z1 = (xs[1] - mu1) * i1;
        float z2 = (xs[2] - mu2) * i2, z3 = (xs[3] - mu3) * i3;
        float a0 = (cst - 0.5f * (z0 * z0 + z1 * z1 + z2 * z2 + z3 * z3)) + lpi;
        float m0a = dppMaxAll(a0);
        float u = __expf(a0 - m0a);
        float s0 = dppSumAll(u);
        double acc = (double)(m0a + __logf(s0));
        u *= (1.0f / s0);

        // m_pre ring (4-deep prefetch), wave-uniform broadcast loads
        const float* mp = m_pre + (size_t)b * T_LEN;
        float g0 = mp[1], g1 = mp[2], g2 = mp[3], g3 = mp[4];

#pragma unroll 1
        for (int t = 1; t < T_LEN; ++t) {
            float mm_c = g0; g0 = g1; g1 = g2; g2 = g3;
            int tp = t + 4; if (tp > T_LEN - 1) tp = T_LEN - 1;
            g3 = mp[tp];

            // emission t (mul path; xs reads issued early; independent of u -> overlaps)
            int o = t * 6;
            float y0 = xs[o], y1 = xs[o + 1], y2 = xs[o + 2], y3 = xs[o + 3];
            float w0 = (y0 - mu0) * i0, w1 = (y1 - mu1) * i1;
            float w2 = (y2 - mu2) * i2, w3 = (y3 - mu3) * i3;
            float lp = cst - 0.5f * (w0 * w0 + w1 * w1 + w2 * w2 + w3 * w3);
            float e_c = __expf(lp - mm_c);

            // q_j = sum_i u[i]*A[i][j] via readlane broadcast (register-only)
            float q0 = 0.f, q1 = 0.f, q2 = 0.f, q3 = 0.f;
#pragma unroll
            for (int gq = 0; gq < 4; ++gq) {
                float s[16];
#pragma unroll
                for (int m = 0; m < 16; ++m) s[m] = rl(u, 16 * gq + m);
#pragma unroll
                for (int k2 = 0; k2 < 4; ++k2) {
                    const int i = 16 * gq + 4 * k2;     // i = 4k+c, k ascending per chain
                    q0 = fmaf(s[4 * k2 + 0], Ac[i + 0], q0);
                    q1 = fmaf(s[4 * k2 + 1], Ac[i + 1], q1);
                    q2 = fmaf(s[4 * k2 + 2], Ac[i + 2], q2);
                    q3 = fmaf(s[4 * k2 + 3], Ac[i + 3], q3);
                }
            }
            u = ((q0 + q1) + (q2 + q3)) * e_c;
            acc += (double)mm_c;
            if ((t & 3) == 0) {          // deferred renorm (rounds 9/10 proven)
                float ss = dppSumAll(u);
                acc += (double)__logf(ss);
                u *= (1.0f / ss);
            }
        }
        float sf = dppSumAll(u);
        acc += (double)__logf(sf);
        if (j == 0) out[b] = (float)acc;
    } else {
        // ---------------- VITERBI: readlane broadcast + ring-8 constant-distance prefetch ----------------
        float lA[64];
        {
            const float4* g = (const float4*)lAg;
#pragma unroll
            for (int k = 0; k < 16; ++k) {
                float4 v = g[j * 16 + k];
                lA[4 * k + 0] = v.x; lA[4 * k + 1] = v.y;
                lA[4 * k + 2] = v.z; lA[4 * k + 3] = v.w;
            }
        }
        float* bb = buf + (size_t)b * T_LEN * 64 + j;

        // t = 0: seed dn, fill ring with lp rows 1..8, then overwrite row 0 with d0
        float dn = bb[0] + lpi;
        float lr[8];
#pragma unroll
        for (int i = 0; i < 8; ++i) lr[i] = bb[(size_t)(1 + i) * 64];
        bb[0] = dn;

        // main: t = 1..2040 in 255 groups of 8; ring slots are compile-time
        // indices (no shifts); load (t+8) vs store (t) distance = 2048 B, alias-free.
#pragma unroll 1
        for (int tb = 1; tb <= 2033; tb += 8) {
#pragma unroll
            for (int q = 0; q < 8; ++q) {
                const int t = tb + q;
                float lp_c = lr[q];
                lr[q] = bb[(size_t)(t + 8) * 64];   // max t+8 = 2048, in-bounds
                VIT_REDUCE(dn);
                dn = fmaxf(fmaxf(m0, m1), fmaxf(m2, m3)) + lp_c;
                bb[(size_t)t * 64] = dn;            // overwrite lp row t with d row t
            }
        }
        // row 2049 (distance >= 9 rows from last store: alias-free)
        float l_last = bb[(size_t)2049 * 64];
        // peel t = 2041..2048 from the ring (no loads)
#pragma unroll
        for (int q = 0; q < 8; ++q) {
            const int t = 2041 + q;
            float lp_c = lr[q];
            VIT_REDUCE(dn);
            dn = fmaxf(fmaxf(m0, m1), fmaxf(m2, m3)) + lp_c;
            bb[(size_t)t * 64] = dn;
        }
        // final t = 2049 (d row 2049 never read downstream: no store)
        {
            float lp_c = l_last;
            VIT_REDUCE(dn);
            dn = fmaxf(fmaxf(m0, m1), fmaxf(m2, m3)) + lp_c;
        }

        float vv = dn; int idx = j;
        waveArgmax(vv, idx);
        if (j == 0) c_last[b] = idx;
    }
}

// ===== psi recompute: persistent lA in regs, grid-stride over (t,b) pairs (round-5 verbatim) =====
extern "C" __global__ __launch_bounds__(256)
void hmm_psi(const float* __restrict__ buf,
             const float* __restrict__ lAg,
             unsigned char* __restrict__ psi)
{
    __shared__ __align__(16) float sd[4][64];
    const int warp = threadIdx.x >> 6;
    const int j = threadIdx.x & 63;
    const int wid = blockIdx.x * 4 + warp;        // 0..8191

    float lA[64];
    {
        const float4* g = (const float4*)lAg;
#pragma unroll
        for (int k = 0; k < 16; ++k) {
            float4 v = g[j * 16 + k];
            lA[4 * k + 0] = v.x; lA[4 * k + 1] = v.y;
            lA[4 * k + 2] = v.z; lA[4 * k + 3] = v.w;
        }
    }
    const float4* dv = (const float4*)sd[warp];
    const int NP = 2049 * B_SZ;

    for (int p = wid; p < NP; p += 8192) {
        const int t = (p >> 7) + 1;
        const int b = p & 127;
        float dval = buf[((size_t)b * T_LEN + (t - 1)) * 64 + j];
        sd[warp][j] = dval;    // same-wave in-order: reads below see it

        // round-5-verbatim argmax tracker (np.argmax first-occurrence semantics)
        float bv0 = -3.4e38f, bv1 = -3.4e38f, bv2 = -3.4e38f, bv3 = -3.4e38f;
        int bi0 = 0, bi1 = 1, bi2 = 2, bi3 = 3;
#pragma unroll
        for (int k = 0; k < 16; ++k) {
            float4 dd = dv[k];
            float v0 = dd.x + lA[4 * k + 0];
            float v1 = dd.y + lA[4 * k + 1];
            float v2 = dd.z + lA[4 * k + 2];
            float v3 = dd.w + lA[4 * k + 3];
            if (v0 > bv0) { bv0 = v0; bi0 = 4 * k + 0; }
            if (v1 > bv1) { bv1 = v1; bi1 = 4 * k + 1; }
            if (v2 > bv2) { bv2 = v2; bi2 = 4 * k + 2; }
            if (v3 > bv3) { bv3 = v3; bi3 = 4 * k + 3; }
        }
        float best = bv0; int bidx = bi0;
        if (bv1 > best || (bv1 == best && bi1 < bidx)) { best = bv1; bidx = bi1; }
        if (bv2 > best || (bv2 == best && bi2 < bidx)) { best = bv2; bidx = bi2; }
        if (bv3 > best || (bv3 == best && bi3 < bidx)) { best = bv3; bidx = bi3; }

        psi[((size_t)t * B_SZ + b) * 64 + j] = (unsigned char)bidx;
    }
}

// ===== per-chunk backpointer composition: wave per (b, g) (round-5 verbatim) =====
extern "C" __global__ __launch_bounds__(256)
void hmm_compose(const unsigned char* __restrict__ psi,
                 unsigned char* __restrict__ mt)
{
    const int w = blockIdx.x * 4 + (threadIdx.x >> 6);   // 0 .. 4223
    const int j = threadIdx.x & 63;
    const int g = w % NCHUNK;
    const int b = w / NCHUNK;
    const int e = (g < NCHUNK - 1) ? g * 64 + 64 : (T_LEN - 1);
    int M = j;
    for (int t = e; t >= g * 64 + 1; --t)
        M = psi[((size_t)t * B_SZ + b) * 64 + M];
    mt[((size_t)g * B_SZ + b) * 64 + j] = (unsigned char)M;
}

// ===== boundary walk + parallel chunk fill: block per batch (round-5 verbatim) =====
extern "C" __global__ __launch_bounds__(64, 1)
void hmm_fill(const unsigned char* __restrict__ psi,
              const unsigned char* __restrict__ mt,
              const int* __restrict__ c_last,
              float* __restrict__ out)
{
    __shared__ int sb[NCHUNK];       // sb[g] = state at t = 64*g
    const int b = blockIdx.x;
    const int g = threadIdx.x;
    const int cl = c_last[b];
    if (g == 0) {
        int cur = cl;
        for (int q = NCHUNK - 1; q >= 0; --q) {
            cur = mt[((size_t)q * B_SZ + b) * 64 + cur];
            sb[q] = cur;
        }
    }
    cfence();   // single wave, in-order DS
    float* oc = out + B_SZ + (size_t)b * T_LEN;
    if (g == NCHUNK) {
        oc[T_LEN - 1] = (float)cl;
    } else if (g < NCHUNK) {
        const int e = (g < NCHUNK - 1) ? g * 64 + 64 : (T_LEN - 1);
        int s = (g < NCHUNK - 1) ? sb[g + 1] : cl;
        for (int t = e; t >= g * 64 + 1; --t) {
            s = psi[((size_t)t * B_SZ + b) * 64 + s];
            oc[t - 1] = (float)s;
        }
    }
}

extern "C" void kernel_launch(void* const* d_in, const int* in_sizes, int n_in,
                              void* d_out, int out_size, void* d_ws, size_t ws_size,
                              hipStream_t stream)
{
    const float* x      = (const float*)d_in[0];
    const float* means  = (const float*)d_in[1];
    const float* stds   = (const float*)d_in[2];
    const float* logA   = (const float*)d_in[3];
    const float* logpi  = (const float*)d_in[4];
    float* out = (float*)d_out;

    // workspace: m_pre overlaps psi region (consumed by hmm_main before hmm_psi writes psi)
    char* base = (char*)d_ws;
    float*         buf   = (float*)base;                                 // 67,174,400 (lp then d, in place)
    unsigned char* psi   = (unsigned char*)(base + 67174400);            // 16,793,600
    float*         m_pre = (float*)(base + 67174400);                    //  1,049,600 (dead after hmm_main)
    unsigned char* mt    = (unsigned char*)(base + 83968000);            //    270,336
    int*           cl    = (int*)(base + 84238336);                      //        512
    float*         lAg   = (float*)(base + 84238848);                    //     16,384
    float*         lpig  = (float*)(base + 84255232);                    //        256

    hipLaunchKernelGGL(hmm_emis, dim3((T_LEN * B_SZ) / 4), dim3(256), 0, stream,
                       x, means, stds, buf, m_pre, logA, logpi, lAg, lpig);
    hipLaunchKernelGGL(hmm_main, dim3(2 * B_SZ), dim3(64), 0, stream,
                       x, means, stds, lAg, lpig, out, buf, m_pre, cl);
    hipLaunchKernelGGL(hmm_psi, dim3(2048), dim3(256), 0, stream, buf, lAg, psi);
    hipLaunchKernelGGL(hmm_compose, dim3((NCHUNK * B_SZ) / 4), dim3(256), 0, stream, psi, mt);
    hipLaunchKernelGGL(hmm_fill, dim3(B_SZ), dim3(64), 0, stream, psi, mt, cl, out);
}